// Round 1
// baseline (263.178 us; speedup 1.0000x reference)
//
#include <hip/hip_runtime.h>
#include <hip/hip_fp16.h>
#include <cmath>

#define Tn 8192
#define Dn 512
#define Fn 2048
#define En 8

typedef _Float16 f16x8 __attribute__((ext_vector_type(8)));
typedef float f32x4 __attribute__((ext_vector_type(4)));

#define BM 64
#define BN 128
#define BK 32
#define LDA 40          // padded K stride (elems) in LDS
#define MAXTILES 136    // ceil(Tn/BM) + En

// ---------------- router: logits, softmax top-1, histogram ----------------
__global__ __launch_bounds__(256) void router_kernel(
    const float* __restrict__ x, const float* __restrict__ Ws,
    const float* __restrict__ bs, int* __restrict__ route,
    float* __restrict__ scale, int* __restrict__ counts)
{
    const int lane = threadIdx.x & 63;
    const int gwave = (blockIdx.x * 256 + threadIdx.x) >> 6;  // 0..1023

    float wreg[8][8];
#pragma unroll
    for (int i = 0; i < 8; ++i) {
        const float4* p = reinterpret_cast<const float4*>(Ws + (lane + 64 * i) * En);
        float4 a = p[0], b = p[1];
        wreg[i][0] = a.x; wreg[i][1] = a.y; wreg[i][2] = a.z; wreg[i][3] = a.w;
        wreg[i][4] = b.x; wreg[i][5] = b.y; wreg[i][6] = b.z; wreg[i][7] = b.w;
    }
    float bsv[8];
#pragma unroll
    for (int e = 0; e < 8; ++e) bsv[e] = bs[e];

    for (int it = 0; it < 8; ++it) {
        int t = gwave * 8 + it;
        float part[8];
#pragma unroll
        for (int e = 0; e < 8; ++e) part[e] = 0.f;
#pragma unroll
        for (int i = 0; i < 8; ++i) {
            float xv = x[(size_t)t * Dn + lane + 64 * i];
#pragma unroll
            for (int e = 0; e < 8; ++e) part[e] = fmaf(xv, wreg[i][e], part[e]);
        }
#pragma unroll
        for (int s = 32; s > 0; s >>= 1) {
#pragma unroll
            for (int e = 0; e < 8; ++e) part[e] += __shfl_xor(part[e], s);
        }
        if (lane == 0) {
            float lg[8];
            lg[0] = part[0] + bsv[0];
            float m = lg[0]; int am = 0;
#pragma unroll
            for (int e = 1; e < 8; ++e) {
                lg[e] = part[e] + bsv[e];
                if (lg[e] > m) { m = lg[e]; am = e; }   // first-max tie rule
            }
            float sum = 0.f;
#pragma unroll
            for (int e = 0; e < 8; ++e) sum += expf(lg[e] - m);
            route[t] = am;
            scale[t] = 1.0f / sum;    // top-1 softmax prob
            atomicAdd(&counts[am], 1);
        }
    }
}

// ---------------- plan: offsets + tile table ----------------
__global__ void plan_kernel(const int* __restrict__ counts, int* __restrict__ offsets,
                            int* __restrict__ nTiles, int* __restrict__ tileExpert,
                            int* __restrict__ tileBase, int* __restrict__ tileEnd)
{
    if (threadIdx.x != 0 || blockIdx.x != 0) return;
    int off = 0, nt = 0;
    for (int e = 0; e < En; ++e) {
        int c = counts[e];
        offsets[e] = off;
        int tiles = (c + BM - 1) / BM;
        for (int r = 0; r < tiles; ++r) {
            tileExpert[nt] = e;
            tileBase[nt] = off + r * BM;
            tileEnd[nt] = off + c;
            ++nt;
        }
        off += c;
    }
    *nTiles = nt;
}

// ---------------- scatter: counting-sort token ids ----------------
__global__ __launch_bounds__(256) void scatter_kernel(
    const int* __restrict__ route, const int* __restrict__ offsets,
    int* __restrict__ cursor, int* __restrict__ order)
{
    int t = blockIdx.x * 256 + threadIdx.x;
    if (t >= Tn) return;
    int e = route[t];
    int pos = atomicAdd(&cursor[e], 1);
    order[offsets[e] + pos] = t;
}

// ---------------- transpose + fp32->fp16 for W1, W2 ----------------
__global__ __launch_bounds__(256) void transpose_cvt_kernel(
    const float* __restrict__ W1, const float* __restrict__ W2,
    _Float16* __restrict__ W1T, _Float16* __restrict__ W2T)
{
    __shared__ float tile[64][65];
    int bx = blockIdx.x;
    const float* in; _Float16* outp; int R, C, tR, tC;
    if (bx < 2048) {            // W1[e]: [D][F] -> W1T[e]: [F][D]
        int e = bx >> 8, t = bx & 255;
        R = Dn; C = Fn; tR = t >> 5; tC = t & 31;
        in = W1 + (size_t)e * Dn * Fn;
        outp = W1T + (size_t)e * Dn * Fn;
    } else {                    // W2[e]: [F][D] -> W2T[e]: [D][F]
        int b2 = bx - 2048;
        int e = b2 >> 8, t = b2 & 255;
        R = Fn; C = Dn; tR = t >> 3; tC = t & 7;
        in = W2 + (size_t)e * Fn * Dn;
        outp = W2T + (size_t)e * Fn * Dn;
    }
    int r0 = tR * 64, c0 = tC * 64;
    int row = threadIdx.x >> 2, cq = threadIdx.x & 3;
#pragma unroll
    for (int i = 0; i < 4; ++i) {
        float4 v = *reinterpret_cast<const float4*>(in + (size_t)(r0 + row) * C + c0 + cq * 16 + i * 4);
        tile[row][cq * 16 + i * 4 + 0] = v.x;
        tile[row][cq * 16 + i * 4 + 1] = v.y;
        tile[row][cq * 16 + i * 4 + 2] = v.z;
        tile[row][cq * 16 + i * 4 + 3] = v.w;
    }
    __syncthreads();
    int col = threadIdx.x >> 2, rq = threadIdx.x & 3;
    f16x8 o0, o1;
#pragma unroll
    for (int i = 0; i < 8; ++i) o0[i] = (_Float16)tile[rq * 16 + i][col];
#pragma unroll
    for (int i = 0; i < 8; ++i) o1[i] = (_Float16)tile[rq * 16 + 8 + i][col];
    size_t base = (size_t)(c0 + col) * R + r0 + rq * 16;
    *reinterpret_cast<f16x8*>(outp + base) = o0;
    *reinterpret_cast<f16x8*>(outp + base + 8) = o1;
}

// ---------------- GEMM1: h = gelu(Xg @ W1 + b1), h stored fp16 ----------------
__global__ __launch_bounds__(256) void gemm1_kernel(
    const float* __restrict__ x, const _Float16* __restrict__ W1T,
    const float* __restrict__ b1, const int* __restrict__ order,
    const int* __restrict__ nTiles, const int* __restrict__ tileExpert,
    const int* __restrict__ tileBase, const int* __restrict__ tileEnd,
    _Float16* __restrict__ hbuf)
{
    __shared__ _Float16 As[2][BM][LDA];
    __shared__ _Float16 Bs[2][BN][LDA];
    const int bt = blockIdx.x;
    if (bt >= *nTiles) return;
    const int e = tileExpert[bt], rowBase = tileBase[bt], rowEnd = tileEnd[bt];
    const int nBase = blockIdx.y * BN;
    const int tid = threadIdx.x;

    // A staging: 64 rows x 32 k; thread -> (row, k-quarter of 8 floats)
    const int ar = tid >> 2, aq = tid & 3;
    const int ia = min(rowBase + ar, Tn - 1);
    const int tokA = order[ia];
    const float* Ap = x + (size_t)tokA * Dn + aq * 8;
    // B staging: 128 n-rows x 32 k of W1T; thread -> (n, k-half of 16 halves)
    const int br = tid >> 1, bh = tid & 1;
    const _Float16* Bp = W1T + (size_t)e * Dn * Fn + (size_t)(nBase + br) * Dn + bh * 16;

    const int lane = tid & 63, w = tid >> 6;
    const int wr = w >> 1, wc = w & 1;
    const int arow = wr * 32 + (lane & 15);
    const int brow = wc * 64 + (lane & 15);
    const int kg = (lane >> 4) * 8;

    f32x4 acc[2][4];
#pragma unroll
    for (int m = 0; m < 2; ++m)
#pragma unroll
        for (int n = 0; n < 4; ++n) acc[m][n] = {0.f, 0.f, 0.f, 0.f};

    float4 a0 = *reinterpret_cast<const float4*>(Ap);
    float4 a1 = *reinterpret_cast<const float4*>(Ap + 4);
    f16x8 bv0 = *reinterpret_cast<const f16x8*>(Bp);
    f16x8 bv1 = *reinterpret_cast<const f16x8*>(Bp + 8);
    {
        f16x8 av;
        av[0] = (_Float16)a0.x; av[1] = (_Float16)a0.y; av[2] = (_Float16)a0.z; av[3] = (_Float16)a0.w;
        av[4] = (_Float16)a1.x; av[5] = (_Float16)a1.y; av[6] = (_Float16)a1.z; av[7] = (_Float16)a1.w;
        *reinterpret_cast<f16x8*>(&As[0][ar][aq * 8]) = av;
        *reinterpret_cast<f16x8*>(&Bs[0][br][bh * 16]) = bv0;
        *reinterpret_cast<f16x8*>(&Bs[0][br][bh * 16 + 8]) = bv1;
    }
    __syncthreads();

    const int NKT = Dn / BK;  // 16
    for (int kt = 0; kt < NKT; ++kt) {
        const int cur = kt & 1;
        if (kt + 1 < NKT) {
            a0 = *reinterpret_cast<const float4*>(Ap + (kt + 1) * BK);
            a1 = *reinterpret_cast<const float4*>(Ap + (kt + 1) * BK + 4);
            bv0 = *reinterpret_cast<const f16x8*>(Bp + (kt + 1) * BK);
            bv1 = *reinterpret_cast<const f16x8*>(Bp + (kt + 1) * BK + 8);
        }
        f16x8 af[2], bf[4];
#pragma unroll
        for (int m = 0; m < 2; ++m)
            af[m] = *reinterpret_cast<const f16x8*>(&As[cur][arow + m * 16][kg]);
#pragma unroll
        for (int n = 0; n < 4; ++n)
            bf[n] = *reinterpret_cast<const f16x8*>(&Bs[cur][brow + n * 16][kg]);
#pragma unroll
        for (int m = 0; m < 2; ++m)
#pragma unroll
            for (int n = 0; n < 4; ++n)
                acc[m][n] = __builtin_amdgcn_mfma_f32_16x16x32_f16(af[m], bf[n], acc[m][n], 0, 0, 0);
        if (kt + 1 < NKT) {
            const int nxt = cur ^ 1;
            f16x8 av;
            av[0] = (_Float16)a0.x; av[1] = (_Float16)a0.y; av[2] = (_Float16)a0.z; av[3] = (_Float16)a0.w;
            av[4] = (_Float16)a1.x; av[5] = (_Float16)a1.y; av[6] = (_Float16)a1.z; av[7] = (_Float16)a1.w;
            *reinterpret_cast<f16x8*>(&As[nxt][ar][aq * 8]) = av;
            *reinterpret_cast<f16x8*>(&Bs[nxt][br][bh * 16]) = bv0;
            *reinterpret_cast<f16x8*>(&Bs[nxt][br][bh * 16 + 8]) = bv1;
        }
        __syncthreads();
    }

    float b1v[4];
#pragma unroll
    for (int n = 0; n < 4; ++n) b1v[n] = b1[(size_t)e * Fn + nBase + brow + n * 16];
#pragma unroll
    for (int m = 0; m < 2; ++m) {
#pragma unroll
        for (int j = 0; j < 4; ++j) {
            int i = rowBase + wr * 32 + m * 16 + (lane >> 4) * 4 + j;
            if (i < rowEnd) {
#pragma unroll
                for (int n = 0; n < 4; ++n) {
                    float v = acc[m][n][j] + b1v[n];
                    float g = 0.5f * v * (1.0f + erff(v * 0.70710678118654752f));
                    hbuf[(size_t)i * Fn + nBase + brow + n * 16] = (_Float16)g;
                }
            }
        }
    }
}

// ---------------- GEMM2: out = (h @ W2 + b2) * prob, scattered ----------------
__global__ __launch_bounds__(256) void gemm2_kernel(
    const _Float16* __restrict__ hbuf, const _Float16* __restrict__ W2T,
    const float* __restrict__ b2, const int* __restrict__ order,
    const float* __restrict__ scale,
    const int* __restrict__ nTiles, const int* __restrict__ tileExpert,
    const int* __restrict__ tileBase, const int* __restrict__ tileEnd,
    float* __restrict__ out)
{
    __shared__ _Float16 As[2][BM][LDA];
    __shared__ _Float16 Bs[2][BN][LDA];
    const int bt = blockIdx.x;
    if (bt >= *nTiles) return;
    const int e = tileExpert[bt], rowBase = tileBase[bt], rowEnd = tileEnd[bt];
    const int nBase = blockIdx.y * BN;
    const int tid = threadIdx.x;

    const int ar = tid >> 2, aq = tid & 3;
    const int ia = min(rowBase + ar, Tn - 1);
    const _Float16* Ap = hbuf + (size_t)ia * Fn + aq * 8;
    const int br = tid >> 1, bh = tid & 1;
    const _Float16* Bp = W2T + (size_t)e * Fn * Dn + (size_t)(nBase + br) * Fn + bh * 16;

    const int lane = tid & 63, w = tid >> 6;
    const int wr = w >> 1, wc = w & 1;
    const int arow = wr * 32 + (lane & 15);
    const int brow = wc * 64 + (lane & 15);
    const int kg = (lane >> 4) * 8;

    f32x4 acc[2][4];
#pragma unroll
    for (int m = 0; m < 2; ++m)
#pragma unroll
        for (int n = 0; n < 4; ++n) acc[m][n] = {0.f, 0.f, 0.f, 0.f};

    f16x8 av = *reinterpret_cast<const f16x8*>(Ap);
    f16x8 bv0 = *reinterpret_cast<const f16x8*>(Bp);
    f16x8 bv1 = *reinterpret_cast<const f16x8*>(Bp + 8);
    *reinterpret_cast<f16x8*>(&As[0][ar][aq * 8]) = av;
    *reinterpret_cast<f16x8*>(&Bs[0][br][bh * 16]) = bv0;
    *reinterpret_cast<f16x8*>(&Bs[0][br][bh * 16 + 8]) = bv1;
    __syncthreads();

    const int NKT = Fn / BK;  // 64
    for (int kt = 0; kt < NKT; ++kt) {
        const int cur = kt & 1;
        if (kt + 1 < NKT) {
            av = *reinterpret_cast<const f16x8*>(Ap + (kt + 1) * BK);
            bv0 = *reinterpret_cast<const f16x8*>(Bp + (kt + 1) * BK);
            bv1 = *reinterpret_cast<const f16x8*>(Bp + (kt + 1) * BK + 8);
        }
        f16x8 af[2], bf[4];
#pragma unroll
        for (int m = 0; m < 2; ++m)
            af[m] = *reinterpret_cast<const f16x8*>(&As[cur][arow + m * 16][kg]);
#pragma unroll
        for (int n = 0; n < 4; ++n)
            bf[n] = *reinterpret_cast<const f16x8*>(&Bs[cur][brow + n * 16][kg]);
#pragma unroll
        for (int m = 0; m < 2; ++m)
#pragma unroll
            for (int n = 0; n < 4; ++n)
                acc[m][n] = __builtin_amdgcn_mfma_f32_16x16x32_f16(af[m], bf[n], acc[m][n], 0, 0, 0);
        if (kt + 1 < NKT) {
            const int nxt = cur ^ 1;
            *reinterpret_cast<f16x8*>(&As[nxt][ar][aq * 8]) = av;
            *reinterpret_cast<f16x8*>(&Bs[nxt][br][bh * 16]) = bv0;
            *reinterpret_cast<f16x8*>(&Bs[nxt][br][bh * 16 + 8]) = bv1;
        }
        __syncthreads();
    }

    float b2v[4];
#pragma unroll
    for (int n = 0; n < 4; ++n) b2v[n] = b2[(size_t)e * Dn + nBase + brow + n * 16];
#pragma unroll
    for (int m = 0; m < 2; ++m) {
#pragma unroll
        for (int j = 0; j < 4; ++j) {
            int i = rowBase + wr * 32 + m * 16 + (lane >> 4) * 4 + j;
            if (i < rowEnd) {
                int tok = order[i];
                float s = scale[tok];
#pragma unroll
                for (int n = 0; n < 4; ++n)
                    out[(size_t)tok * Dn + nBase + brow + n * 16] = (acc[m][n][j] + b2v[n]) * s;
            }
        }
    }
}

extern "C" void kernel_launch(void* const* d_in, const int* in_sizes, int n_in,
                              void* d_out, int out_size, void* d_ws, size_t ws_size,
                              hipStream_t stream) {
    const float* x  = (const float*)d_in[0];
    const float* Ws = (const float*)d_in[1];
    const float* bs = (const float*)d_in[2];
    const float* W1 = (const float*)d_in[3];
    const float* b1 = (const float*)d_in[4];
    const float* W2 = (const float*)d_in[5];
    const float* b2 = (const float*)d_in[6];
    float* out = (float*)d_out;

    char* ws = (char*)d_ws;
    int* counts     = (int*)(ws + 0);
    int* cursor     = (int*)(ws + 64);
    int* offsets    = (int*)(ws + 128);
    int* nTiles     = (int*)(ws + 192);
    int* tileExpert = (int*)(ws + 256);
    int* tileBase   = (int*)(ws + 1024);
    int* tileEnd    = (int*)(ws + 2048);
    int* route      = (int*)(ws + 4096);
    float* scale    = (float*)(ws + 4096 + 4 * Tn);
    int* order      = (int*)(ws + 4096 + 8 * Tn);
    _Float16* W1T   = (_Float16*)(ws + (1 << 20));
    _Float16* W2T   = W1T + (size_t)En * Dn * Fn;
    _Float16* hbuf  = W2T + (size_t)En * Fn * Dn;

    hipMemsetAsync(ws, 0, 256, stream);
    router_kernel<<<256, 256, 0, stream>>>(x, Ws, bs, route, scale, counts);
    plan_kernel<<<1, 64, 0, stream>>>(counts, offsets, nTiles, tileExpert, tileBase, tileEnd);
    scatter_kernel<<<Tn / 256, 256, 0, stream>>>(route, offsets, cursor, order);
    transpose_cvt_kernel<<<4096, 256, 0, stream>>>(W1, W2, W1T, W2T);
    gemm1_kernel<<<dim3(MAXTILES, Fn / BN), 256, 0, stream>>>(
        x, W1T, b1, order, nTiles, tileExpert, tileBase, tileEnd, hbuf);
    gemm2_kernel<<<dim3(MAXTILES, Dn / BN), 256, 0, stream>>>(
        hbuf, W2T, b2, order, scale, nTiles, tileExpert, tileBase, tileEnd, out);
}

// Round 2
// 142.991 us; speedup vs baseline: 1.8405x; 1.8405x over previous
//
#include <hip/hip_runtime.h>
#include <hip/hip_fp16.h>
#include <cmath>

#define Tn 8192
#define Dn 512
#define Fn 2048
#define En 8

typedef _Float16 f16x8 __attribute__((ext_vector_type(8)));
typedef float f32x4 __attribute__((ext_vector_type(4)));

#define BM 64
#define BN 128
#define BK 32
#define LDA 40          // padded K stride (elems) in LDS
#define MAXTILES 136    // ceil(Tn/BM) + En

// ---------------- router: logits, softmax top-1, LDS histogram + local rank ----------------
__global__ __launch_bounds__(256) void router_kernel(
    const float* __restrict__ x, const float* __restrict__ Ws,
    const float* __restrict__ bs, int* __restrict__ route,
    float* __restrict__ scale, int* __restrict__ poslocal,
    int* __restrict__ blockCounts)
{
    __shared__ int hist[8];
    const int tid = threadIdx.x;
    if (tid < 8) hist[tid] = 0;
    __syncthreads();

    const int lane = tid & 63;
    const int w = tid >> 6;                    // wave 0..3
    const int tokBase = blockIdx.x * 32 + w * 8;

    float wreg[8][8];
#pragma unroll
    for (int i = 0; i < 8; ++i) {
        const float4* p = reinterpret_cast<const float4*>(Ws + (lane + 64 * i) * En);
        float4 a = p[0], b = p[1];
        wreg[i][0] = a.x; wreg[i][1] = a.y; wreg[i][2] = a.z; wreg[i][3] = a.w;
        wreg[i][4] = b.x; wreg[i][5] = b.y; wreg[i][6] = b.z; wreg[i][7] = b.w;
    }
    float bsv[8];
#pragma unroll
    for (int e = 0; e < 8; ++e) bsv[e] = bs[e];

    for (int it = 0; it < 8; ++it) {
        int t = tokBase + it;
        float part[8];
#pragma unroll
        for (int e = 0; e < 8; ++e) part[e] = 0.f;
#pragma unroll
        for (int i = 0; i < 8; ++i) {
            float xv = x[(size_t)t * Dn + lane + 64 * i];
#pragma unroll
            for (int e = 0; e < 8; ++e) part[e] = fmaf(xv, wreg[i][e], part[e]);
        }
#pragma unroll
        for (int s = 32; s > 0; s >>= 1) {
#pragma unroll
            for (int e = 0; e < 8; ++e) part[e] += __shfl_xor(part[e], s);
        }
        if (lane == 0) {
            float lg[8];
            lg[0] = part[0] + bsv[0];
            float m = lg[0]; int am = 0;
#pragma unroll
            for (int e = 1; e < 8; ++e) {
                lg[e] = part[e] + bsv[e];
                if (lg[e] > m) { m = lg[e]; am = e; }   // first-max tie rule
            }
            float sum = 0.f;
#pragma unroll
            for (int e = 0; e < 8; ++e) sum += expf(lg[e] - m);
            route[t] = am;
            scale[t] = 1.0f / sum;                 // top-1 softmax prob
            poslocal[t] = atomicAdd(&hist[am], 1); // LDS atomic: local rank
        }
    }
    __syncthreads();
    if (tid < 8) blockCounts[blockIdx.x * 8 + tid] = hist[tid];
}

// ---------------- plan: prefix sums (no atomics) + tile table ----------------
__global__ __launch_bounds__(256) void plan_kernel(
    const int* __restrict__ blockCounts,   // [256][8]
    int* __restrict__ base,                // [256][8] out
    int* __restrict__ nTiles, int* __restrict__ tileExpert,
    int* __restrict__ tileBase, int* __restrict__ tileEnd)
{
    __shared__ int cnt[256 * 8];
    __shared__ int groupSum[32 * 8];
    __shared__ int groupBase[32 * 8];
    __shared__ int totals[8];
    __shared__ int offsets_s[8];
    const int tid = threadIdx.x;
    for (int i = tid; i < 2048; i += 256) cnt[i] = blockCounts[i];
    __syncthreads();
    const int e = tid & 7, g = tid >> 3;   // 32 groups of 8 blocks
    {
        int s = 0;
#pragma unroll
        for (int b = g * 8; b < g * 8 + 8; ++b) s += cnt[b * 8 + e];
        groupSum[g * 8 + e] = s;
    }
    __syncthreads();
    if (tid < 8) {
        int run = 0;
        for (int gg = 0; gg < 32; ++gg) {
            groupBase[gg * 8 + tid] = run;
            run += groupSum[gg * 8 + tid];
        }
        totals[tid] = run;
    }
    __syncthreads();
    if (tid == 0) {
        int off = 0, nt = 0;
        for (int ee = 0; ee < En; ++ee) {
            offsets_s[ee] = off;
            int c = totals[ee];
            int tiles = (c + BM - 1) / BM;
            for (int r = 0; r < tiles; ++r) {
                tileExpert[nt] = ee;
                tileBase[nt] = off + r * BM;
                tileEnd[nt] = off + c;
                ++nt;
            }
            off += c;
        }
        *nTiles = nt;
    }
    __syncthreads();
    {
        int run = offsets_s[e] + groupBase[g * 8 + e];
#pragma unroll
        for (int b = g * 8; b < g * 8 + 8; ++b) {
            base[b * 8 + e] = run;
            run += cnt[b * 8 + e];
        }
    }
}

// ---------------- scatter: pure writes, no atomics ----------------
__global__ __launch_bounds__(256) void scatter_kernel(
    const int* __restrict__ route, const int* __restrict__ poslocal,
    const int* __restrict__ base, int* __restrict__ order)
{
    int t = blockIdx.x * 256 + threadIdx.x;
    if (t >= Tn) return;
    int e = route[t];
    int rb = t >> 5;                       // router block of 32 tokens
    order[base[rb * 8 + e] + poslocal[t]] = t;
}

// ---------------- transpose + fp32->fp16 for W1, W2 ----------------
__global__ __launch_bounds__(256) void transpose_cvt_kernel(
    const float* __restrict__ W1, const float* __restrict__ W2,
    _Float16* __restrict__ W1T, _Float16* __restrict__ W2T)
{
    __shared__ float tile[64][65];
    int bx = blockIdx.x;
    const float* in; _Float16* outp; int R, C, tR, tC;
    if (bx < 2048) {            // W1[e]: [D][F] -> W1T[e]: [F][D]
        int e = bx >> 8, t = bx & 255;
        R = Dn; C = Fn; tR = t >> 5; tC = t & 31;
        in = W1 + (size_t)e * Dn * Fn;
        outp = W1T + (size_t)e * Dn * Fn;
    } else {                    // W2[e]: [F][D] -> W2T[e]: [D][F]
        int b2 = bx - 2048;
        int e = b2 >> 8, t = b2 & 255;
        R = Fn; C = Dn; tR = t >> 3; tC = t & 7;
        in = W2 + (size_t)e * Fn * Dn;
        outp = W2T + (size_t)e * Fn * Dn;
    }
    int r0 = tR * 64, c0 = tC * 64;
    int row = threadIdx.x >> 2, cq = threadIdx.x & 3;
#pragma unroll
    for (int i = 0; i < 4; ++i) {
        float4 v = *reinterpret_cast<const float4*>(in + (size_t)(r0 + row) * C + c0 + cq * 16 + i * 4);
        tile[row][cq * 16 + i * 4 + 0] = v.x;
        tile[row][cq * 16 + i * 4 + 1] = v.y;
        tile[row][cq * 16 + i * 4 + 2] = v.z;
        tile[row][cq * 16 + i * 4 + 3] = v.w;
    }
    __syncthreads();
    int col = threadIdx.x >> 2, rq = threadIdx.x & 3;
    f16x8 o0, o1;
#pragma unroll
    for (int i = 0; i < 8; ++i) o0[i] = (_Float16)tile[rq * 16 + i][col];
#pragma unroll
    for (int i = 0; i < 8; ++i) o1[i] = (_Float16)tile[rq * 16 + 8 + i][col];
    size_t base = (size_t)(c0 + col) * R + r0 + rq * 16;
    *reinterpret_cast<f16x8*>(outp + base) = o0;
    *reinterpret_cast<f16x8*>(outp + base + 8) = o1;
}

// ---------------- GEMM1: h = gelu(Xg @ W1 + b1), h stored fp16 ----------------
__global__ __launch_bounds__(256) void gemm1_kernel(
    const float* __restrict__ x, const _Float16* __restrict__ W1T,
    const float* __restrict__ b1, const int* __restrict__ order,
    const int* __restrict__ nTiles, const int* __restrict__ tileExpert,
    const int* __restrict__ tileBase, const int* __restrict__ tileEnd,
    _Float16* __restrict__ hbuf)
{
    __shared__ _Float16 As[2][BM][LDA];
    __shared__ _Float16 Bs[2][BN][LDA];
    const int bt = blockIdx.x;
    if (bt >= *nTiles) return;
    const int e = tileExpert[bt], rowBase = tileBase[bt], rowEnd = tileEnd[bt];
    const int nBase = blockIdx.y * BN;
    const int tid = threadIdx.x;

    const int ar = tid >> 2, aq = tid & 3;
    const int ia = min(rowBase + ar, Tn - 1);
    const int tokA = order[ia];
    const float* Ap = x + (size_t)tokA * Dn + aq * 8;
    const int br = tid >> 1, bh = tid & 1;
    const _Float16* Bp = W1T + (size_t)e * Dn * Fn + (size_t)(nBase + br) * Dn + bh * 16;

    const int lane = tid & 63, w = tid >> 6;
    const int wr = w >> 1, wc = w & 1;
    const int arow = wr * 32 + (lane & 15);
    const int brow = wc * 64 + (lane & 15);
    const int kg = (lane >> 4) * 8;

    f32x4 acc[2][4];
#pragma unroll
    for (int m = 0; m < 2; ++m)
#pragma unroll
        for (int n = 0; n < 4; ++n) acc[m][n] = {0.f, 0.f, 0.f, 0.f};

    float4 a0 = *reinterpret_cast<const float4*>(Ap);
    float4 a1 = *reinterpret_cast<const float4*>(Ap + 4);
    f16x8 bv0 = *reinterpret_cast<const f16x8*>(Bp);
    f16x8 bv1 = *reinterpret_cast<const f16x8*>(Bp + 8);
    {
        f16x8 av;
        av[0] = (_Float16)a0.x; av[1] = (_Float16)a0.y; av[2] = (_Float16)a0.z; av[3] = (_Float16)a0.w;
        av[4] = (_Float16)a1.x; av[5] = (_Float16)a1.y; av[6] = (_Float16)a1.z; av[7] = (_Float16)a1.w;
        *reinterpret_cast<f16x8*>(&As[0][ar][aq * 8]) = av;
        *reinterpret_cast<f16x8*>(&Bs[0][br][bh * 16]) = bv0;
        *reinterpret_cast<f16x8*>(&Bs[0][br][bh * 16 + 8]) = bv1;
    }
    __syncthreads();

    const int NKT = Dn / BK;  // 16
    for (int kt = 0; kt < NKT; ++kt) {
        const int cur = kt & 1;
        if (kt + 1 < NKT) {
            a0 = *reinterpret_cast<const float4*>(Ap + (kt + 1) * BK);
            a1 = *reinterpret_cast<const float4*>(Ap + (kt + 1) * BK + 4);
            bv0 = *reinterpret_cast<const f16x8*>(Bp + (kt + 1) * BK);
            bv1 = *reinterpret_cast<const f16x8*>(Bp + (kt + 1) * BK + 8);
        }
        f16x8 af[2], bf[4];
#pragma unroll
        for (int m = 0; m < 2; ++m)
            af[m] = *reinterpret_cast<const f16x8*>(&As[cur][arow + m * 16][kg]);
#pragma unroll
        for (int n = 0; n < 4; ++n)
            bf[n] = *reinterpret_cast<const f16x8*>(&Bs[cur][brow + n * 16][kg]);
#pragma unroll
        for (int m = 0; m < 2; ++m)
#pragma unroll
            for (int n = 0; n < 4; ++n)
                acc[m][n] = __builtin_amdgcn_mfma_f32_16x16x32_f16(af[m], bf[n], acc[m][n], 0, 0, 0);
        if (kt + 1 < NKT) {
            const int nxt = cur ^ 1;
            f16x8 av;
            av[0] = (_Float16)a0.x; av[1] = (_Float16)a0.y; av[2] = (_Float16)a0.z; av[3] = (_Float16)a0.w;
            av[4] = (_Float16)a1.x; av[5] = (_Float16)a1.y; av[6] = (_Float16)a1.z; av[7] = (_Float16)a1.w;
            *reinterpret_cast<f16x8*>(&As[nxt][ar][aq * 8]) = av;
            *reinterpret_cast<f16x8*>(&Bs[nxt][br][bh * 16]) = bv0;
            *reinterpret_cast<f16x8*>(&Bs[nxt][br][bh * 16 + 8]) = bv1;
        }
        __syncthreads();
    }

    float b1v[4];
#pragma unroll
    for (int n = 0; n < 4; ++n) b1v[n] = b1[(size_t)e * Fn + nBase + brow + n * 16];
#pragma unroll
    for (int m = 0; m < 2; ++m) {
#pragma unroll
        for (int j = 0; j < 4; ++j) {
            int i = rowBase + wr * 32 + m * 16 + (lane >> 4) * 4 + j;
            if (i < rowEnd) {
#pragma unroll
                for (int n = 0; n < 4; ++n) {
                    float v = acc[m][n][j] + b1v[n];
                    float g = 0.5f * v * (1.0f + erff(v * 0.70710678118654752f));
                    hbuf[(size_t)i * Fn + nBase + brow + n * 16] = (_Float16)g;
                }
            }
        }
    }
}

// ---------------- GEMM2: out = (h @ W2 + b2) * prob, scattered ----------------
__global__ __launch_bounds__(256) void gemm2_kernel(
    const _Float16* __restrict__ hbuf, const _Float16* __restrict__ W2T,
    const float* __restrict__ b2, const int* __restrict__ order,
    const float* __restrict__ scale,
    const int* __restrict__ nTiles, const int* __restrict__ tileExpert,
    const int* __restrict__ tileBase, const int* __restrict__ tileEnd,
    float* __restrict__ out)
{
    __shared__ _Float16 As[2][BM][LDA];
    __shared__ _Float16 Bs[2][BN][LDA];
    const int bt = blockIdx.x;
    if (bt >= *nTiles) return;
    const int e = tileExpert[bt], rowBase = tileBase[bt], rowEnd = tileEnd[bt];
    const int nBase = blockIdx.y * BN;
    const int tid = threadIdx.x;

    const int ar = tid >> 2, aq = tid & 3;
    const int ia = min(rowBase + ar, Tn - 1);
    const _Float16* Ap = hbuf + (size_t)ia * Fn + aq * 8;
    const int br = tid >> 1, bh = tid & 1;
    const _Float16* Bp = W2T + (size_t)e * Fn * Dn + (size_t)(nBase + br) * Fn + bh * 16;

    const int lane = tid & 63, w = tid >> 6;
    const int wr = w >> 1, wc = w & 1;
    const int arow = wr * 32 + (lane & 15);
    const int brow = wc * 64 + (lane & 15);
    const int kg = (lane >> 4) * 8;

    f32x4 acc[2][4];
#pragma unroll
    for (int m = 0; m < 2; ++m)
#pragma unroll
        for (int n = 0; n < 4; ++n) acc[m][n] = {0.f, 0.f, 0.f, 0.f};

    f16x8 av = *reinterpret_cast<const f16x8*>(Ap);
    f16x8 bv0 = *reinterpret_cast<const f16x8*>(Bp);
    f16x8 bv1 = *reinterpret_cast<const f16x8*>(Bp + 8);
    *reinterpret_cast<f16x8*>(&As[0][ar][aq * 8]) = av;
    *reinterpret_cast<f16x8*>(&Bs[0][br][bh * 16]) = bv0;
    *reinterpret_cast<f16x8*>(&Bs[0][br][bh * 16 + 8]) = bv1;
    __syncthreads();

    const int NKT = Fn / BK;  // 64
    for (int kt = 0; kt < NKT; ++kt) {
        const int cur = kt & 1;
        if (kt + 1 < NKT) {
            av = *reinterpret_cast<const f16x8*>(Ap + (kt + 1) * BK);
            bv0 = *reinterpret_cast<const f16x8*>(Bp + (kt + 1) * BK);
            bv1 = *reinterpret_cast<const f16x8*>(Bp + (kt + 1) * BK + 8);
        }
        f16x8 af[2], bf[4];
#pragma unroll
        for (int m = 0; m < 2; ++m)
            af[m] = *reinterpret_cast<const f16x8*>(&As[cur][arow + m * 16][kg]);
#pragma unroll
        for (int n = 0; n < 4; ++n)
            bf[n] = *reinterpret_cast<const f16x8*>(&Bs[cur][brow + n * 16][kg]);
#pragma unroll
        for (int m = 0; m < 2; ++m)
#pragma unroll
            for (int n = 0; n < 4; ++n)
                acc[m][n] = __builtin_amdgcn_mfma_f32_16x16x32_f16(af[m], bf[n], acc[m][n], 0, 0, 0);
        if (kt + 1 < NKT) {
            const int nxt = cur ^ 1;
            *reinterpret_cast<f16x8*>(&As[nxt][ar][aq * 8]) = av;
            *reinterpret_cast<f16x8*>(&Bs[nxt][br][bh * 16]) = bv0;
            *reinterpret_cast<f16x8*>(&Bs[nxt][br][bh * 16 + 8]) = bv1;
        }
        __syncthreads();
    }

    float b2v[4];
#pragma unroll
    for (int n = 0; n < 4; ++n) b2v[n] = b2[(size_t)e * Dn + nBase + brow + n * 16];
#pragma unroll
    for (int m = 0; m < 2; ++m) {
#pragma unroll
        for (int j = 0; j < 4; ++j) {
            int i = rowBase + wr * 32 + m * 16 + (lane >> 4) * 4 + j;
            if (i < rowEnd) {
                int tok = order[i];
                float s = scale[tok];
#pragma unroll
                for (int n = 0; n < 4; ++n)
                    out[(size_t)tok * Dn + nBase + brow + n * 16] = (acc[m][n][j] + b2v[n]) * s;
            }
        }
    }
}

extern "C" void kernel_launch(void* const* d_in, const int* in_sizes, int n_in,
                              void* d_out, int out_size, void* d_ws, size_t ws_size,
                              hipStream_t stream) {
    const float* x  = (const float*)d_in[0];
    const float* Ws = (const float*)d_in[1];
    const float* bs = (const float*)d_in[2];
    const float* W1 = (const float*)d_in[3];
    const float* b1 = (const float*)d_in[4];
    const float* W2 = (const float*)d_in[5];
    const float* b2 = (const float*)d_in[6];
    float* out = (float*)d_out;

    char* ws = (char*)d_ws;
    int* nTiles      = (int*)(ws + 0);
    int* tileExpert  = (int*)(ws + 256);
    int* tileBase    = (int*)(ws + 1024);
    int* tileEnd     = (int*)(ws + 2048);
    int* route       = (int*)(ws + 4096);
    float* scale     = (float*)(ws + 4096 + 4 * Tn);
    int* poslocal    = (int*)(ws + 4096 + 8 * Tn);
    int* order       = (int*)(ws + 4096 + 12 * Tn);
    int* blockCounts = (int*)(ws + 4096 + 16 * Tn);
    int* base        = (int*)(ws + 4096 + 16 * Tn + 8192);
    _Float16* W1T    = (_Float16*)(ws + (1 << 20));
    _Float16* W2T    = W1T + (size_t)En * Dn * Fn;
    _Float16* hbuf   = W2T + (size_t)En * Fn * Dn;

    router_kernel<<<256, 256, 0, stream>>>(x, Ws, bs, route, scale, poslocal, blockCounts);
    plan_kernel<<<1, 256, 0, stream>>>(blockCounts, base, nTiles, tileExpert, tileBase, tileEnd);
    scatter_kernel<<<Tn / 256, 256, 0, stream>>>(route, poslocal, base, order);
    transpose_cvt_kernel<<<4096, 256, 0, stream>>>(W1, W2, W1T, W2T);
    gemm1_kernel<<<dim3(MAXTILES, Fn / BN), 256, 0, stream>>>(
        x, W1T, b1, order, nTiles, tileExpert, tileBase, tileEnd, hbuf);
    gemm2_kernel<<<dim3(MAXTILES, Dn / BN), 256, 0, stream>>>(
        hbuf, W2T, b2, order, scale, nTiles, tileExpert, tileBase, tileEnd, out);
}